// Round 21
// baseline (99.180 us; speedup 1.0000x reference)
//
#include <hip/hip_runtime.h>

#define GRID_H 20
#define GRID_W 80
#define NCH 264
#define K 256
#define NPIX 128   // 16x8 glyph pixels

typedef __attribute__((ext_vector_type(8))) short short8;
typedef __attribute__((ext_vector_type(4))) float f32x4;
typedef __attribute__((ext_vector_type(8))) unsigned short u16x8;

static __device__ __forceinline__ unsigned short f2bf(float f) {
    unsigned int u = __builtin_bit_cast(unsigned int, f);
    u += 0x7FFFu + ((u >> 16) & 1u);   // round-to-nearest-even
    return (unsigned short)(u >> 16);
}

// Swizzled byte offset within a 32KB pixel-half (R9/R12-proven layout):
// 64 rows (local pixel) x 512B (256 bf16 channels), XOR (pl&7)<<4.
static __device__ __forceinline__ int bswz(int pl, int clbyte) {
    return (pl * 512 + clbyte) ^ ((pl & 7) << 4);
}

// Pack cm (f32 [256 ch][128 px]) -> ws: two 32KB pixel-halves whose LINEAR
// byte order equals the main kernel's swizzled LDS layout (R12/R16-proven).
__global__ void prep_kernel(const float* __restrict__ cm,
                            unsigned short* __restrict__ ws) {
    int i = blockIdx.x * 256 + threadIdx.x;   // 0..4095 chunks of 16B
    int p  = i & 127;                         // pixel 0..127
    int c8 = i >> 7;                          // channel-group of 8 (0..31)
    int hf = p >> 6, pl = p & 63;
    u16x8 pk;
    #pragma unroll
    for (int j = 0; j < 8; ++j) pk[j] = f2bf(cm[(c8 * 8 + j) * NPIX + p]);
    *reinterpret_cast<u16x8*>((char*)ws + hf * 32768 + bswz(pl, c8 * 16)) = pk;
}

// NOTE: plain 1-arg launch_bounds only (2-arg form miscompiled MFMA, R2/R3/R7).
// Every global_load_lds batch gets its own nearby following barrier (R17 race).
template <bool USE_WS>
__global__ __launch_bounds__(320) void ansi_kernel(
        const float* __restrict__ data,
        const float* __restrict__ cm,
        const unsigned short* __restrict__ ws,
        float* __restrict__ out) {
    // Double-buffered pixel-halves of B: half-1 DMA overlaps half-0 MFMA.
    __shared__ alignas(16) unsigned char ldsB[2][32768];
    // Wave-PRIVATE epilogue staging (R9-proven): [wave][line][slot][x*3+ch]
    __shared__ alignas(16) float S[5][2][16][24];   // 15 KB; total ~80 KB

    const int blk = blockIdx.x;
    const int b = blk / GRID_H;
    const int h = blk % GRID_H;
    const float* dbase = data + (size_t)(b * GRID_H + h) * GRID_W * NCH;
    const int t = threadIdx.x;
    const int wave = t >> 6;
    const int lane = t & 63;
    const int mrow = lane & 15;     // cell within M-tile
    const int g    = lane >> 4;     // k-group
    const int cell0 = wave * 16;

    // ---- issue DMA half0 -> buf0 (R12-proven shape) ----
    if (USE_WS) {
        const char* src = (const char*)ws;
        #pragma unroll
        for (int it = 0; it < 6; ++it) {
            int j = it * 320 + t;
            __builtin_amdgcn_global_load_lds(
                (const __attribute__((address_space(1))) void*)(src + (size_t)j * 16),
                (__attribute__((address_space(3))) void*)&ldsB[0][(it * 320 + wave * 64) * 16],
                16, 0, 0);
        }
        if (t < 128) {   // tail chunks 1920..2047 (waves 0,1 full)
            int j = 1920 + t;
            __builtin_amdgcn_global_load_lds(
                (const __attribute__((address_space(1))) void*)(src + (size_t)j * 16),
                (__attribute__((address_space(3))) void*)&ldsB[0][(1920 + wave * 64) * 16],
                16, 0, 0);
        }
    } else {
        for (int i = t; i < 64 * 32; i += 320) {
            int pl = i & 63;
            int cg = i >> 6;
            const float* src = cm + (size_t)cg * 8 * NPIX + pl;
            u16x8 pk;
            #pragma unroll
            for (int j = 0; j < 8; ++j) pk[j] = f2bf(src[j * NPIX]);
            *reinterpret_cast<u16x8*>(&ldsB[0][bswz(pl, cg * 16)]) = pk;
        }
    }

    // ---- fg/bg: lanes 0..15 one cell each, distribute via shfl ----
    float fb[6] = {0.f, 0.f, 0.f, 0.f, 0.f, 0.f};
    if (lane < 16) {
        const float* q = dbase + (size_t)(cell0 + lane) * NCH + 256;
        float4 a = *reinterpret_cast<const float4*>(q);      // fg_bold, fg.rgb
        float4 c = *reinterpret_cast<const float4*>(q + 4);  // bg_bold, bg.rgb
        float fs = 0.5f * a.x + 0.5f;
        float bs = 0.5f * c.x + 0.5f;
        fb[0] = bs * c.y; fb[1] = bs * c.z; fb[2] = bs * c.w;
        fb[3] = fs * a.y - fb[0];
        fb[4] = fs * a.z - fb[1];
        fb[5] = fs * a.w - fb[2];
    }
    float bgv[4][3], dv[4][3];
    #pragma unroll
    for (int r = 0; r < 4; ++r) {
        int srcl = g * 4 + r;        // source lane = local cell index
        #pragma unroll
        for (int j = 0; j < 3; ++j) {
            bgv[r][j] = __shfl(fb[j], srcl);
            dv[r][j]  = __shfl(fb[3 + j], srcl);
        }
    }

    // ---- load + pack A once (full K=256): 8 x bf16x8 ----
    const float* arow = dbase + (size_t)(cell0 + mrow) * NCH + g * 8;
    short8 apk[8];
    #pragma unroll
    for (int ks = 0; ks < 8; ++ks) {
        float4 a0 = *reinterpret_cast<const float4*>(arow + ks * 32);
        float4 a1 = *reinterpret_cast<const float4*>(arow + ks * 32 + 4);
        u16x8 ap;
        ap[0] = f2bf(a0.x); ap[1] = f2bf(a0.y); ap[2] = f2bf(a0.z); ap[3] = f2bf(a0.w);
        ap[4] = f2bf(a1.x); ap[5] = f2bf(a1.y); ap[6] = f2bf(a1.z); ap[7] = f2bf(a1.w);
        apk[ks] = __builtin_bit_cast(short8, ap);
    }

    f32x4 acc[8];
    #pragma unroll
    for (int n = 0; n < 8; ++n) acc[n] = (f32x4){0.f, 0.f, 0.f, 0.f};

    __syncthreads();   // bar#1: buf0 DMA + A/fgbg loads drained

    // ---- issue DMA half1 -> buf1 (flies under the half0 MFMAs) ----
    if (USE_WS) {
        const char* src = (const char*)ws + 32768;
        #pragma unroll
        for (int it = 0; it < 6; ++it) {
            int j = it * 320 + t;
            __builtin_amdgcn_global_load_lds(
                (const __attribute__((address_space(1))) void*)(src + (size_t)j * 16),
                (__attribute__((address_space(3))) void*)&ldsB[1][(it * 320 + wave * 64) * 16],
                16, 0, 0);
        }
        if (t < 128) {
            int j = 1920 + t;
            __builtin_amdgcn_global_load_lds(
                (const __attribute__((address_space(1))) void*)(src + (size_t)j * 16),
                (__attribute__((address_space(3))) void*)&ldsB[1][(1920 + wave * 64) * 16],
                16, 0, 0);
        }
    } else {
        for (int i = t; i < 64 * 32; i += 320) {
            int pl = i & 63;
            int cg = i >> 6;
            const float* src = cm + (size_t)cg * 8 * NPIX + 64 + pl;
            u16x8 pk;
            #pragma unroll
            for (int j = 0; j < 8; ++j) pk[j] = f2bf(src[j * NPIX]);
            *reinterpret_cast<u16x8*>(&ldsB[1][bswz(pl, cg * 16)]) = pk;
        }
    }

    // ---- GEMM half0 from buf0 ----
    #pragma unroll
    for (int ks = 0; ks < 8; ++ks) {
        const int kbase = ks * 32 + g * 8;
        #pragma unroll
        for (int n = 0; n < 4; ++n) {
            int pl = n * 16 + mrow;
            short8 bfrag = *reinterpret_cast<short8*>(&ldsB[0][bswz(pl, kbase * 2)]);
            acc[n] = __builtin_amdgcn_mfma_f32_16x16x32_bf16(
                apk[ks], bfrag, acc[n], 0, 0, 0);
        }
    }

    __syncthreads();   // bar#2: buf1 DMA drained

    // ---- epilogue setup (R16-proven mapping) ----
    const int col = lane & 15;
    f32x4* out4 = (f32x4*)out;          // ext_vector type for NT builtin
    const size_t rowf4 = (size_t)(b * 320 + h * 16) * 480 + wave * 96;
    const int line_sel = col >> 3;
    const int x3 = (col & 7) * 3;
    const f32x4* Sw = (const f32x4*)&S[wave][0][0][0];   // 192 f32x4

    // ---- GEMM half1 with epilogue passes 0..3 INJECTED every 2nd ks:
    // stores touch only finalized acc[0..3] + wave-private S (no dependency
    // on the running MFMAs), so the store bursts drain under the MFMA stream
    // at 4 injection points instead of one monolithic burst (R20).
    #pragma unroll
    for (int ks = 0; ks < 8; ++ks) {
        const int kbase = ks * 32 + g * 8;
        #pragma unroll
        for (int n = 0; n < 4; ++n) {
            int pl = n * 16 + mrow;
            short8 bfrag = *reinterpret_cast<short8*>(&ldsB[1][bswz(pl, kbase * 2)]);
            acc[4 + n] = __builtin_amdgcn_mfma_f32_16x16x32_bf16(
                apk[ks], bfrag, acc[4 + n], 0, 0, 0);
        }
        if (ks & 1) {
            const int pass = ks >> 1;          // 0..3, static under unroll
            #pragma unroll
            for (int r = 0; r < 4; ++r) {
                float raw = acc[pass][r];
                float* o = &S[wave][line_sel][r * 4 + g][x3];
                o[0] = bgv[r][0] + raw * dv[r][0];
                o[1] = bgv[r][1] + raw * dv[r][1];
                o[2] = bgv[r][2] + raw * dv[r][2];
            }
            #pragma unroll
            for (int q = 0; q < 3; ++q) {
                int j = q * 64 + lane;            // 0..191
                int line = (j >= 96) ? 1 : 0;
                int rem = j - 96 * line;          // 0..95 = cell*6 + s
                int c = rem / 6;
                int s = rem - 6 * c;
                f32x4 v = Sw[line * 96 + ((c & 3) * 4 + (c >> 2)) * 6 + s];
                __builtin_nontemporal_store(
                    v, &out4[rowf4 + (size_t)(pass * 2 + line) * 480 + rem]);
            }
        }
    }

    // ---- epilogue passes 4..7 (half1 results) ----
    #pragma unroll
    for (int pass = 4; pass < 8; ++pass) {
        #pragma unroll
        for (int r = 0; r < 4; ++r) {
            float raw = acc[pass][r];
            float* o = &S[wave][line_sel][r * 4 + g][x3];
            o[0] = bgv[r][0] + raw * dv[r][0];
            o[1] = bgv[r][1] + raw * dv[r][1];
            o[2] = bgv[r][2] + raw * dv[r][2];
        }
        #pragma unroll
        for (int q = 0; q < 3; ++q) {
            int j = q * 64 + lane;            // 0..191
            int line = (j >= 96) ? 1 : 0;
            int rem = j - 96 * line;          // 0..95 = cell*6 + s
            int c = rem / 6;
            int s = rem - 6 * c;
            f32x4 v = Sw[line * 96 + ((c & 3) * 4 + (c >> 2)) * 6 + s];
            __builtin_nontemporal_store(
                v, &out4[rowf4 + (size_t)(pass * 2 + line) * 480 + rem]);
        }
    }
}

extern "C" void kernel_launch(void* const* d_in, const int* in_sizes, int n_in,
                              void* d_out, int out_size, void* d_ws, size_t ws_size,
                              hipStream_t stream) {
    (void)in_sizes; (void)n_in; (void)out_size;
    const float* data = (const float*)d_in[0];
    const float* cm   = (const float*)d_in[1];
    float* out        = (float*)d_out;
    const int nblocks = 128 * GRID_H;   // one block per (b, h)
    if (ws_size >= 65536) {
        prep_kernel<<<16, 256, 0, stream>>>(cm, (unsigned short*)d_ws);
        ansi_kernel<true><<<nblocks, 320, 0, stream>>>(
            data, cm, (const unsigned short*)d_ws, out);
    } else {
        ansi_kernel<false><<<nblocks, 320, 0, stream>>>(data, cm, nullptr, out);
    }
}

// Round 22
// 97.837 us; speedup vs baseline: 1.0137x; 1.0137x over previous
//
#include <hip/hip_runtime.h>

#define GRID_H 20
#define GRID_W 80
#define NCH 264
#define K 256
#define NPIX 128   // 16x8 glyph pixels

typedef __attribute__((ext_vector_type(8))) short short8;
typedef __attribute__((ext_vector_type(4))) float f32x4;
typedef __attribute__((ext_vector_type(8))) unsigned short u16x8;

static __device__ __forceinline__ unsigned short f2bf(float f) {
    unsigned int u = __builtin_bit_cast(unsigned int, f);
    u += 0x7FFFu + ((u >> 16) & 1u);   // round-to-nearest-even
    return (unsigned short)(u >> 16);
}

// Swizzled byte offset within a 32KB pixel-half (R9/R12-proven layout):
// 64 rows (local pixel) x 512B (256 bf16 channels), XOR (pl&7)<<4.
static __device__ __forceinline__ int bswz(int pl, int clbyte) {
    return (pl * 512 + clbyte) ^ ((pl & 7) << 4);
}

// Pack cm (f32 [256 ch][128 px]) -> ws: two 32KB pixel-halves whose LINEAR
// byte order equals the main kernel's swizzled LDS layout (R12/R16-proven).
__global__ void prep_kernel(const float* __restrict__ cm,
                            unsigned short* __restrict__ ws) {
    int i = blockIdx.x * 256 + threadIdx.x;   // 0..4095 chunks of 16B
    int p  = i & 127;                         // pixel 0..127
    int c8 = i >> 7;                          // channel-group of 8 (0..31)
    int hf = p >> 6, pl = p & 63;
    u16x8 pk;
    #pragma unroll
    for (int j = 0; j < 8; ++j) pk[j] = f2bf(cm[(c8 * 8 + j) * NPIX + p]);
    *reinterpret_cast<u16x8*>((char*)ws + hf * 32768 + bswz(pl, c8 * 16)) = pk;
}

// NOTE: plain 1-arg launch_bounds only (2-arg form miscompiled MFMA, R2/R3/R7).
// Every global_load_lds batch gets its own nearby following barrier (R17 race).
template <bool USE_WS>
__global__ __launch_bounds__(320) void ansi_kernel(
        const float* __restrict__ data,
        const float* __restrict__ cm,
        const unsigned short* __restrict__ ws,
        float* __restrict__ out) {
    // Double-buffered pixel-halves of B: half-1 DMA overlaps half-0 MFMA.
    __shared__ alignas(16) unsigned char ldsB[2][32768];
    // Wave-PRIVATE epilogue staging (R9-proven): [wave][line][slot][x*3+ch]
    __shared__ alignas(16) float S[5][2][16][24];   // 15 KB; total ~80 KB

    const int blk = blockIdx.x;
    const int b = blk / GRID_H;
    const int h = blk % GRID_H;
    const float* dbase = data + (size_t)(b * GRID_H + h) * GRID_W * NCH;
    const int t = threadIdx.x;
    const int wave = t >> 6;
    const int lane = t & 63;
    const int mrow = lane & 15;     // cell within M-tile
    const int g    = lane >> 4;     // k-group
    const int cell0 = wave * 16;

    // ---- issue DMA half0 -> buf0 (R12-proven shape) ----
    if (USE_WS) {
        const char* src = (const char*)ws;
        #pragma unroll
        for (int it = 0; it < 6; ++it) {
            int j = it * 320 + t;
            __builtin_amdgcn_global_load_lds(
                (const __attribute__((address_space(1))) void*)(src + (size_t)j * 16),
                (__attribute__((address_space(3))) void*)&ldsB[0][(it * 320 + wave * 64) * 16],
                16, 0, 0);
        }
        if (t < 128) {   // tail chunks 1920..2047 (waves 0,1 full)
            int j = 1920 + t;
            __builtin_amdgcn_global_load_lds(
                (const __attribute__((address_space(1))) void*)(src + (size_t)j * 16),
                (__attribute__((address_space(3))) void*)&ldsB[0][(1920 + wave * 64) * 16],
                16, 0, 0);
        }
    } else {
        for (int i = t; i < 64 * 32; i += 320) {
            int pl = i & 63;
            int cg = i >> 6;
            const float* src = cm + (size_t)cg * 8 * NPIX + pl;
            u16x8 pk;
            #pragma unroll
            for (int j = 0; j < 8; ++j) pk[j] = f2bf(src[j * NPIX]);
            *reinterpret_cast<u16x8*>(&ldsB[0][bswz(pl, cg * 16)]) = pk;
        }
    }

    // ---- fg/bg: lanes 0..15 one cell each, distribute via shfl ----
    float fb[6] = {0.f, 0.f, 0.f, 0.f, 0.f, 0.f};
    if (lane < 16) {
        const float* q = dbase + (size_t)(cell0 + lane) * NCH + 256;
        float4 a = *reinterpret_cast<const float4*>(q);      // fg_bold, fg.rgb
        float4 c = *reinterpret_cast<const float4*>(q + 4);  // bg_bold, bg.rgb
        float fs = 0.5f * a.x + 0.5f;
        float bs = 0.5f * c.x + 0.5f;
        fb[0] = bs * c.y; fb[1] = bs * c.z; fb[2] = bs * c.w;
        fb[3] = fs * a.y - fb[0];
        fb[4] = fs * a.z - fb[1];
        fb[5] = fs * a.w - fb[2];
    }
    float bgv[4][3], dv[4][3];
    #pragma unroll
    for (int r = 0; r < 4; ++r) {
        int srcl = g * 4 + r;        // source lane = local cell index
        #pragma unroll
        for (int j = 0; j < 3; ++j) {
            bgv[r][j] = __shfl(fb[j], srcl);
            dv[r][j]  = __shfl(fb[3 + j], srcl);
        }
    }

    // ---- load + pack A once (full K=256): 8 x bf16x8 ----
    const float* arow = dbase + (size_t)(cell0 + mrow) * NCH + g * 8;
    short8 apk[8];
    #pragma unroll
    for (int ks = 0; ks < 8; ++ks) {
        float4 a0 = *reinterpret_cast<const float4*>(arow + ks * 32);
        float4 a1 = *reinterpret_cast<const float4*>(arow + ks * 32 + 4);
        u16x8 ap;
        ap[0] = f2bf(a0.x); ap[1] = f2bf(a0.y); ap[2] = f2bf(a0.z); ap[3] = f2bf(a0.w);
        ap[4] = f2bf(a1.x); ap[5] = f2bf(a1.y); ap[6] = f2bf(a1.z); ap[7] = f2bf(a1.w);
        apk[ks] = __builtin_bit_cast(short8, ap);
    }

    f32x4 acc[8];
    #pragma unroll
    for (int n = 0; n < 8; ++n) acc[n] = (f32x4){0.f, 0.f, 0.f, 0.f};

    __syncthreads();   // bar#1: buf0 DMA + A/fgbg loads drained

    // ---- issue DMA half1 -> buf1 (flies under the half0 MFMAs) ----
    if (USE_WS) {
        const char* src = (const char*)ws + 32768;
        #pragma unroll
        for (int it = 0; it < 6; ++it) {
            int j = it * 320 + t;
            __builtin_amdgcn_global_load_lds(
                (const __attribute__((address_space(1))) void*)(src + (size_t)j * 16),
                (__attribute__((address_space(3))) void*)&ldsB[1][(it * 320 + wave * 64) * 16],
                16, 0, 0);
        }
        if (t < 128) {
            int j = 1920 + t;
            __builtin_amdgcn_global_load_lds(
                (const __attribute__((address_space(1))) void*)(src + (size_t)j * 16),
                (__attribute__((address_space(3))) void*)&ldsB[1][(1920 + wave * 64) * 16],
                16, 0, 0);
        }
    } else {
        for (int i = t; i < 64 * 32; i += 320) {
            int pl = i & 63;
            int cg = i >> 6;
            const float* src = cm + (size_t)cg * 8 * NPIX + 64 + pl;
            u16x8 pk;
            #pragma unroll
            for (int j = 0; j < 8; ++j) pk[j] = f2bf(src[j * NPIX]);
            *reinterpret_cast<u16x8*>(&ldsB[1][bswz(pl, cg * 16)]) = pk;
        }
    }

    // ---- GEMM half0 from buf0 ----
    #pragma unroll
    for (int ks = 0; ks < 8; ++ks) {
        const int kbase = ks * 32 + g * 8;
        #pragma unroll
        for (int n = 0; n < 4; ++n) {
            int pl = n * 16 + mrow;
            short8 bfrag = *reinterpret_cast<short8*>(&ldsB[0][bswz(pl, kbase * 2)]);
            acc[n] = __builtin_amdgcn_mfma_f32_16x16x32_bf16(
                apk[ks], bfrag, acc[n], 0, 0, 0);
        }
    }

    __syncthreads();   // bar#2: buf1 DMA drained

    // ---- epilogue setup (R16-proven mapping) ----
    const int col = lane & 15;
    f32x4* out4 = (f32x4*)out;          // ext_vector type for NT builtin
    const size_t rowf4 = (size_t)(b * 320 + h * 16) * 480 + wave * 96;
    const int line_sel = col >> 3;
    const int x3 = (col & 7) * 3;
    const f32x4* Sw = (const f32x4*)&S[wave][0][0][0];   // 192 f32x4

    // ---- EPILOGUE FIRST HALF (passes 0..3, acc[0..3] final): these 24 NT
    // stores/thread drain UNDER the half1 GEMM below (store pipe || MFMA).
    #pragma unroll
    for (int pass = 0; pass < 4; ++pass) {
        #pragma unroll
        for (int r = 0; r < 4; ++r) {
            float raw = acc[pass][r];
            float* o = &S[wave][line_sel][r * 4 + g][x3];
            o[0] = bgv[r][0] + raw * dv[r][0];
            o[1] = bgv[r][1] + raw * dv[r][1];
            o[2] = bgv[r][2] + raw * dv[r][2];
        }
        #pragma unroll
        for (int q = 0; q < 3; ++q) {
            int j = q * 64 + lane;            // 0..191
            int line = (j >= 96) ? 1 : 0;
            int rem = j - 96 * line;          // 0..95 = cell*6 + s
            int c = rem / 6;
            int s = rem - 6 * c;
            f32x4 v = Sw[line * 96 + ((c & 3) * 4 + (c >> 2)) * 6 + s];
            __builtin_nontemporal_store(
                v, &out4[rowf4 + (size_t)(pass * 2 + line) * 480 + rem]);
        }
    }

    // ---- GEMM half1 from buf1 ----
    #pragma unroll
    for (int ks = 0; ks < 8; ++ks) {
        const int kbase = ks * 32 + g * 8;
        #pragma unroll
        for (int n = 0; n < 4; ++n) {
            int pl = n * 16 + mrow;
            short8 bfrag = *reinterpret_cast<short8*>(&ldsB[1][bswz(pl, kbase * 2)]);
            acc[4 + n] = __builtin_amdgcn_mfma_f32_16x16x32_bf16(
                apk[ks], bfrag, acc[4 + n], 0, 0, 0);
        }
    }

    // ---- EPILOGUE SECOND HALF (passes 4..7) ----
    #pragma unroll
    for (int pass = 4; pass < 8; ++pass) {
        #pragma unroll
        for (int r = 0; r < 4; ++r) {
            float raw = acc[pass][r];
            float* o = &S[wave][line_sel][r * 4 + g][x3];
            o[0] = bgv[r][0] + raw * dv[r][0];
            o[1] = bgv[r][1] + raw * dv[r][1];
            o[2] = bgv[r][2] + raw * dv[r][2];
        }
        #pragma unroll
        for (int q = 0; q < 3; ++q) {
            int j = q * 64 + lane;            // 0..191
            int line = (j >= 96) ? 1 : 0;
            int rem = j - 96 * line;          // 0..95 = cell*6 + s
            int c = rem / 6;
            int s = rem - 6 * c;
            f32x4 v = Sw[line * 96 + ((c & 3) * 4 + (c >> 2)) * 6 + s];
            __builtin_nontemporal_store(
                v, &out4[rowf4 + (size_t)(pass * 2 + line) * 480 + rem]);
        }
    }
}

extern "C" void kernel_launch(void* const* d_in, const int* in_sizes, int n_in,
                              void* d_out, int out_size, void* d_ws, size_t ws_size,
                              hipStream_t stream) {
    (void)in_sizes; (void)n_in; (void)out_size;
    const float* data = (const float*)d_in[0];
    const float* cm   = (const float*)d_in[1];
    float* out        = (float*)d_out;
    const int nblocks = 128 * GRID_H;   // one block per (b, h)
    if (ws_size >= 65536) {
        prep_kernel<<<16, 256, 0, stream>>>(cm, (unsigned short*)d_ws);
        ansi_kernel<true><<<nblocks, 320, 0, stream>>>(
            data, cm, (const unsigned short*)d_ws, out);
    } else {
        ansi_kernel<false><<<nblocks, 320, 0, stream>>>(data, cm, nullptr, out);
    }
}